// Round 16
// baseline (180.270 us; speedup 1.0000x reference)
//
#include <hip/hip_runtime.h>

#define D 128
#define SCAN_B 1024

static inline int ceil_div_ll(long long a, int b) { return (int)((a + b - 1) / b); }

typedef unsigned int uint32;
typedef unsigned char uchar;
typedef __attribute__((ext_vector_type(8))) short short8;   // 8 x bf16 (4 VGPRs)
typedef __attribute__((ext_vector_type(4))) float f32x4;    // MFMA C/D

__device__ __forceinline__ float blo(uint32 u) { return __uint_as_float(u << 16); }
__device__ __forceinline__ float bhi(uint32 u) { return __uint_as_float(u & 0xffff0000u); }
__device__ __forceinline__ uint32 bpack(float a, float b) {   // 2x f32 -> bf16x2 RTNE
    uint32 ua = __float_as_uint(a), ub = __float_as_uint(b);
    ua += 0x7fffu + ((ua >> 16) & 1u);
    ub += 0x7fffu + ((ub >> 16) & 1u);
    return (ua >> 16) | (ub & 0xffff0000u);
}

// physical XCD id (0..7), wave-uniform [HW-verified: learn_hip m09]
__device__ __forceinline__ uint32 xcd_id() {
    uint32 x;
    asm volatile("s_getreg_b32 %0, hwreg(HW_REG_XCC_ID)" : "=s"(x));
    return x & 7u;
}

// local (XCD-L2) histogram add: no device-scope coherence round-trip needed,
// since all updaters of replica `xcd` share that XCD's L2 (atomicity at L2).
__device__ __forceinline__ void col_add(uint32* col8, long long n, uint32 xcd, int c) {
    __hip_atomic_fetch_add(&col8[(long long)xcd * n + c], 1u,
                           __ATOMIC_RELAXED, __HIP_MEMORY_SCOPE_WORKGROUP);
}

// FUSED, roles INTERLEAVED (1 count : 5 cvt per 6 blocks, cvt remainder, 8 wprep).
// Count: row-degree via DEVICE atomic (return value = global rank -> rank8),
//        col-degree via XCD-LOCAL replica atomic (no return needed).
__global__ __launch_bounds__(256) void k_fused(
        const int2* __restrict__ rows2, const int2* __restrict__ cols2,
        uint32* __restrict__ cntrow, uint32* __restrict__ col8,
        uchar* __restrict__ rank8, int E2, int odd,
        const int* __restrict__ rows, const int* __restrict__ cols,
        const float4* __restrict__ x, uint4* __restrict__ xh, long long totcvt,
        const float* __restrict__ Wm, uint4* __restrict__ wfrag,
        int ncount, int ncvt, int cvtLeft, int n) {
    const int b = blockIdx.x;
    int role, idx;
    if (b < 6 * ncount) {
        const int g = b / 6, p = b - g * 6;
        if (p == 0) { role = 0; idx = g; }
        else        { role = 1; idx = g * 5 + (p - 1); }
    } else if (b < 6 * ncount + cvtLeft) {
        role = 1; idx = 5 * ncount + (b - 6 * ncount);
    } else {
        role = 2; idx = b - 6 * ncount - cvtLeft;
    }

    if (role == 0) {
        const uint32 xcd = xcd_id();
        const int t = idx * 256 + threadIdx.x;
        if (t < E2) {
            const int2 r2 = rows2[t];
            const int2 c2 = cols2[t];
            const uint32 o0 = atomicAdd(&cntrow[r2.x], 1u);   // device scope, global rank
            col_add(col8, n, xcd, c2.x);
            const uint32 o1 = atomicAdd(&cntrow[r2.y], 1u);
            col_add(col8, n, xcd, c2.y);
            uchar2 rk;
            rk.x = (uchar)o0;
            rk.y = (uchar)o1;
            *(uchar2*)(rank8 + 2 * t) = rk;
        } else if (t == E2 && odd) {
            const uint32 o = atomicAdd(&cntrow[rows[2 * E2]], 1u);
            col_add(col8, n, xcd, cols[2 * E2]);
            rank8[2 * E2] = (uchar)o;
        }
    } else if (role == 1) {
        if (idx >= ncvt) return;
        const long long i = (long long)idx * 256 + threadIdx.x;
        if (i < totcvt) {
            const float4 a = x[i * 2];
            const float4 c = x[i * 2 + 1];
            uint4 o;
            o.x = bpack(a.x, a.y); o.y = bpack(a.z, a.w);
            o.z = bpack(c.x, c.y); o.w = bpack(c.z, c.w);
            xh[i] = o;
        }
    } else {
        // wprep: lane l of entry (kq*8+jt) holds W[jt*16+(l&15)][kq*32+(l>>4)*8..+7]
        const int t = idx * 256 + threadIdx.x;
        if (t >= 2048) return;
        const int l = t & 63;
        const int pair = t >> 6;
        const int kq = pair >> 3;
        const int jt = pair & 7;
        const int s = l & 15;
        const int g = l >> 4;
        const float* src = Wm + ((long long)(jt * 16 + s) << 7) + kq * 32 + g * 8;
        const float4 w0 = *(const float4*)(src);
        const float4 w1 = *(const float4*)(src + 4);
        uint4 o;
        o.x = bpack(w0.x, w0.y); o.y = bpack(w0.z, w0.w);
        o.z = bpack(w1.x, w1.y); o.w = bpack(w1.z, w1.w);
        wfrag[pair * 64 + l] = o;
    }
}

// Local exclusive scan of row-degrees -> rp (IN PLACE over cntrow), bsum.
// ALSO sums the 8 col replicas and writes dinv (f32) over replica 0 (element-
// wise safe: col8[i] is read only by thread i, written by thread i after reads).
__global__ __launch_bounds__(SCAN_B) void k_scan1(uint32* __restrict__ rpcnt,
                                                  uint32* __restrict__ col8,
                                                  int* __restrict__ bsum, int n) {
    __shared__ int sh[SCAN_B];
    const int tid = threadIdx.x;
    const int i = blockIdx.x * SCAN_B + tid;
    int v = (i < n) ? (int)rpcnt[i] : 0;
    sh[tid] = v;
    __syncthreads();
    for (int off = 1; off < SCAN_B; off <<= 1) {
        int t = (tid >= off) ? sh[tid - off] : 0;
        __syncthreads();
        sh[tid] += t;
        __syncthreads();
    }
    if (i < n) {
        rpcnt[i] = (uint32)(sh[tid] - v);          // LOCAL exclusive, in place
        uint32 s = 0;
#pragma unroll
        for (int k = 0; k < 8; ++k) s += col8[(long long)k * n + i];
        ((float*)col8)[i] = rsqrtf((float)(s + 1u));
    }
    if (tid == SCAN_B - 1) bsum[blockIdx.x] = sh[SCAN_B - 1];
}

// exclusive scan of bsum in place (single block)
__global__ __launch_bounds__(SCAN_B) void k_scan2(int* __restrict__ bsum, int nb) {
    __shared__ int sh[SCAN_B];
    const int tid = threadIdx.x;
    int v = (tid < nb) ? bsum[tid] : 0;
    sh[tid] = v;
    __syncthreads();
    for (int off = 1; off < SCAN_B; off <<= 1) {
        int t = (tid >= off) ? sh[tid - off] : 0;
        __syncthreads();
        sh[tid] += t;
        __syncthreads();
    }
    if (tid < nb) bsum[tid] = sh[tid] - v;
}

// ATOMIC-FREE CSR fill: slot = rp[r] + bsum[r>>10] + rank8[e]; col only (4 B)
__global__ void k_fill(const int2* __restrict__ rows2, const int2* __restrict__ cols2,
                       const uchar* __restrict__ rank8, const int* __restrict__ rp,
                       const int* __restrict__ bsum, int* __restrict__ e4,
                       int E2, int odd,
                       const int* __restrict__ rows, const int* __restrict__ cols) {
    int t = blockIdx.x * blockDim.x + threadIdx.x;
    if (t < E2) {
        const int2 r2 = rows2[t];
        const int2 c2 = cols2[t];
        const uchar2 rk = *(const uchar2*)(rank8 + 2 * t);
        e4[rp[r2.x] + bsum[r2.x >> 10] + rk.x] = c2.x;
        e4[rp[r2.y] + bsum[r2.y >> 10] + rk.y] = c2.y;
    } else if (t == E2 && odd) {
        const int r = rows[2 * E2];
        e4[rp[r] + bsum[r >> 10] + rank8[2 * E2]] = cols[2 * E2];
    }
}

// weighted hop on bf16: out[r] = dv_r*( dv_r*xh[r] + sum_c dinv[c]*xh[c] )
// ONE ROW PER 64-LANE WAVE, 4 B (bf16x2)/lane payload gathers. dinv[c] loads
// are wave-uniform broadcasts. Unroll 8, clamped-index + zeroed-weight tail.
__global__ __launch_bounds__(256) void k_spmm(const uint32* __restrict__ xh,
                                              const int* __restrict__ rp,
                                              const int* __restrict__ bsum,
                                              const int* __restrict__ e4,
                                              const float* __restrict__ dinv,
                                              uint32* __restrict__ outh, int n, int Etot) {
    const int row = blockIdx.x * 4 + (threadIdx.x >> 6);
    if (row >= n) return;
    const int l = threadIdx.x & 63;

    const float dv = dinv[row];
    const uint32 sv = xh[(long long)row * 64 + l];
    float alo = dv * blo(sv);
    float ahi = dv * bhi(sv);

    int e = rp[row] + bsum[row >> 10];
    const int end = (row + 1 < n) ? (rp[row + 1] + bsum[(row + 1) >> 10]) : Etot;
    while (e < end) {
        const int last = end - 1;
        int c[8];
#pragma unroll
        for (int k = 0; k < 8; ++k) {
            const int i = (e + k < last) ? e + k : last;
            c[k] = e4[i];
        }
        float w[8];
#pragma unroll
        for (int k = 0; k < 8; ++k)
            w[k] = (e + k <= last) ? dinv[c[k]] : 0.0f;
        uint32 v[8];
#pragma unroll
        for (int k = 0; k < 8; ++k) v[k] = xh[(long long)c[k] * 64 + l];
#pragma unroll
        for (int k = 0; k < 8; ++k) { alo += w[k] * blo(v[k]); ahi += w[k] * bhi(v[k]); }
        e += 8;
    }

    outh[(long long)row * 64 + l] = bpack(dv * alo, dv * ahi);
}

// C[r][:] = bf16(A[r][:]) @ bf16(W)^T + b via mfma_f32_16x16x32_bf16.
// Block = 4 waves; wave = 64 rows x 64 cols (acc 64 VGPR) -> 4 blocks/CU.
// Tail waves clamp to [n-64, n): duplicate identical stores, no OOB reads.
__global__ __launch_bounds__(256, 4) void k_gemm(const short8* __restrict__ A8,
                                                 const short8* __restrict__ wfrag,
                                                 const float* __restrict__ bias,
                                                 float* __restrict__ xout, int n) {
    const int wid = threadIdx.x >> 6;
    const int rg = wid >> 1;           // row group (0/1): 64 rows each
    const int cg = wid & 1;            // col group (0/1): 64 cols each
    const int l = threadIdx.x & 63;
    const int ls = l & 15;
    const int lg = l >> 4;
    long long row0 = (long long)blockIdx.x * 128 + rg * 64;
    if (row0 + 64 > n) row0 = (long long)n - 64;

    float breg[4];
#pragma unroll
    for (int jt = 0; jt < 4; ++jt) breg[jt] = bias[cg * 64 + jt * 16 + ls];

    f32x4 acc[4][4] = {};

#pragma unroll
    for (int kq = 0; kq < 4; ++kq) {
        short8 af[4];
#pragma unroll
        for (int m = 0; m < 4; ++m)
            af[m] = A8[(row0 + m * 16 + ls) * 16 + kq * 4 + lg];
#pragma unroll
        for (int jt = 0; jt < 4; ++jt) {
            const short8 bf = wfrag[(kq * 8 + cg * 4 + jt) * 64 + l];
#pragma unroll
            for (int m = 0; m < 4; ++m)
                acc[m][jt] = __builtin_amdgcn_mfma_f32_16x16x32_bf16(
                    af[m], bf, acc[m][jt], 0, 0, 0);
        }
    }

#pragma unroll
    for (int m = 0; m < 4; ++m) {
#pragma unroll
        for (int q = 0; q < 4; ++q) {
            const long long row = row0 + m * 16 + lg * 4 + q;
            float* orow = xout + (row << 7) + cg * 64;
#pragma unroll
            for (int jt = 0; jt < 4; ++jt)
                orow[jt * 16 + ls] = acc[m][jt][q] + breg[jt];
        }
    }
}

extern "C" void kernel_launch(void* const* d_in, const int* in_sizes, int n_in,
                              void* d_out, int out_size, void* d_ws, size_t ws_size,
                              hipStream_t stream) {
    const float* x = (const float*)d_in[0];
    const int* ei = (const int*)d_in[1];
    const float* Wm = (const float*)d_in[2];
    const float* bias = (const float*)d_in[3];
    float* out = (float*)d_out;

    const int n = in_sizes[0] / D;
    const int E = in_sizes[1] / 2;
    const int E2 = E >> 1;
    const int odd = E & 1;
    const int NB = (n + SCAN_B - 1) / SCAN_B;

    char* ws = (char*)d_ws;
    size_t off = 0;
    auto alloc = [&](long long bytes) {
        void* p = ws + off;
        off += (size_t)((bytes + 511) & ~511LL);
        return p;
    };
    uint32* cntrow = (uint32*)alloc((long long)n * 4);      // row hist -> rp in place
    uint32* col8   = (uint32*)alloc((long long)n * 8 * 4);  // 8 XCD-local col replicas -> dinv
    int* bsum      = (int*)alloc((long long)SCAN_B * 4);
    uchar* rank8   = (uchar*)alloc((long long)E);           // per-edge global row rank
    int* e4        = (int*)alloc((long long)E * 4);         // CSR col only
    uint4* xh      = (uint4*)alloc((long long)n * 256);     // bf16 x; reused as hop-2 out
    uint4* y1h     = (uint4*)alloc((long long)n * 256);     // bf16 hop-1 out
    uint4* wfrag   = (uint4*)alloc(2048LL * 16);            // 32 KB B-fragments
    int* rp        = (int*)cntrow;
    float* dinv    = (float*)col8;

    const int* rows = ei;
    const int* cols = ei + E;
    const int2* rows2 = (const int2*)rows;
    const int2* cols2 = (const int2*)cols;

    const int B = 256;
    const long long totcvt = (long long)n * 16;             // uint4s
    const int ncount = ceil_div_ll(E2 + 1, B);
    const int ncvt = ceil_div_ll(totcvt, B);
    const int cvtLeft = (ncvt > 5 * ncount) ? (ncvt - 5 * ncount) : 0;
    const int grid_fused = 6 * ncount + cvtLeft + 8;

    hipMemsetAsync(cntrow, 0, (size_t)n * 4, stream);
    hipMemsetAsync(col8, 0, (size_t)n * 32, stream);
    // count (row: device atomics+rank; col: XCD-local) || cvt || wprep
    k_fused<<<grid_fused, B, 0, stream>>>(
        rows2, cols2, cntrow, col8, rank8, E2, odd, rows, cols,
        (const float4*)x, xh, totcvt, Wm, wfrag, ncount, ncvt, cvtLeft, n);

    k_scan1<<<NB, SCAN_B, 0, stream>>>(cntrow, col8, bsum, n);  // rp + dinv in place
    k_scan2<<<1, SCAN_B, 0, stream>>>(bsum, NB);
    k_fill<<<ceil_div_ll(E2 + 1, B), B, 0, stream>>>(
        rows2, cols2, rank8, rp, bsum, e4, E2, odd, rows, cols);

    // hop 1: y1 = Anorm @ xh ; hop 2: xh = Anorm @ y1 (xh dead after hop 1)
    k_spmm<<<ceil_div_ll(n, 4), B, 0, stream>>>(
        (const uint32*)xh, rp, bsum, e4, dinv, (uint32*)y1h, n, E);
    k_spmm<<<ceil_div_ll(n, 4), B, 0, stream>>>(
        (const uint32*)y1h, rp, bsum, e4, dinv, (uint32*)xh, n, E);

    k_gemm<<<ceil_div_ll(n, 128), B, 0, stream>>>(
        (const short8*)xh, (const short8*)wfrag, bias, out, n);
}

// Round 17
// 177.598 us; speedup vs baseline: 1.0150x; 1.0150x over previous
//
#include <hip/hip_runtime.h>

#define D 128
#define SCAN_B 1024

static inline int ceil_div_ll(long long a, int b) { return (int)((a + b - 1) / b); }

typedef unsigned int uint32;
typedef __attribute__((ext_vector_type(8))) short short8;   // 8 x bf16 (4 VGPRs)
typedef __attribute__((ext_vector_type(4))) float f32x4;    // MFMA C/D

__device__ __forceinline__ float blo(uint32 u) { return __uint_as_float(u << 16); }
__device__ __forceinline__ float bhi(uint32 u) { return __uint_as_float(u & 0xffff0000u); }
__device__ __forceinline__ uint32 bpack(float a, float b) {   // 2x f32 -> bf16x2 RTNE
    uint32 ua = __float_as_uint(a), ub = __float_as_uint(b);
    ua += 0x7fffu + ((ua >> 16) & 1u);
    ub += 0x7fffu + ((ub >> 16) & 1u);
    return (ua >> 16) | (ub & 0xffff0000u);
}

// FUSED, roles INTERLEAVED (1 count : 5 cvt per 6 blocks, cvt remainder, 8 wprep).
// Packed histogram cnt = (rowdeg<<16)|coldeg; row atomic's return = global rank.
__global__ __launch_bounds__(256) void k_fused(
        const int2* __restrict__ rows2, const int2* __restrict__ cols2,
        uint32* __restrict__ cnt, ushort* __restrict__ rank16, int E2, int odd,
        const int* __restrict__ rows, const int* __restrict__ cols,
        const float4* __restrict__ x, uint4* __restrict__ xh, long long totcvt,
        const float* __restrict__ Wm, uint4* __restrict__ wfrag,
        int ncount, int ncvt, int cvtLeft) {
    const int b = blockIdx.x;
    int role, idx;
    if (b < 6 * ncount) {
        const int g = b / 6, p = b - g * 6;
        if (p == 0) { role = 0; idx = g; }
        else        { role = 1; idx = g * 5 + (p - 1); }
    } else if (b < 6 * ncount + cvtLeft) {
        role = 1; idx = 5 * ncount + (b - 6 * ncount);
    } else {
        role = 2; idx = b - 6 * ncount - cvtLeft;
    }

    if (role == 0) {
        const int t = idx * 256 + threadIdx.x;
        if (t < E2) {
            const int2 r2 = rows2[t];
            const int2 c2 = cols2[t];
            const uint32 o0 = atomicAdd(&cnt[r2.x], 0x10000u);
            atomicAdd(&cnt[c2.x], 1u);
            const uint32 o1 = atomicAdd(&cnt[r2.y], 0x10000u);
            atomicAdd(&cnt[c2.y], 1u);
            ushort2 rk;
            rk.x = (ushort)(o0 >> 16);
            rk.y = (ushort)(o1 >> 16);
            *(ushort2*)(rank16 + 2 * t) = rk;
        } else if (t == E2 && odd) {
            const uint32 o = atomicAdd(&cnt[rows[2 * E2]], 0x10000u);
            atomicAdd(&cnt[cols[2 * E2]], 1u);
            rank16[2 * E2] = (ushort)(o >> 16);
        }
    } else if (role == 1) {
        if (idx >= ncvt) return;
        const long long i = (long long)idx * 256 + threadIdx.x;
        if (i < totcvt) {
            const float4 a = x[i * 2];
            const float4 c = x[i * 2 + 1];
            uint4 o;
            o.x = bpack(a.x, a.y); o.y = bpack(a.z, a.w);
            o.z = bpack(c.x, c.y); o.w = bpack(c.z, c.w);
            xh[i] = o;
        }
    } else {
        // wprep: lane l of entry (kq*8+jt) holds W[jt*16+(l&15)][kq*32+(l>>4)*8..+7]
        const int t = idx * 256 + threadIdx.x;
        if (t >= 2048) return;
        const int l = t & 63;
        const int pair = t >> 6;
        const int kq = pair >> 3;
        const int jt = pair & 7;
        const int s = l & 15;
        const int g = l >> 4;
        const float* src = Wm + ((long long)(jt * 16 + s) << 7) + kq * 32 + g * 8;
        const float4 w0 = *(const float4*)(src);
        const float4 w1 = *(const float4*)(src + 4);
        uint4 o;
        o.x = bpack(w0.x, w0.y); o.y = bpack(w0.z, w0.w);
        o.z = bpack(w1.x, w1.y); o.w = bpack(w1.z, w1.w);
        wfrag[pair * 64 + l] = o;
    }
}

// FUSED scan+zscale: [0,NB): local exclusive scan of row-degrees -> rp, bsum.
//                    [NB,+): z0 = dinv * xh in place; writes dinv[] (f32).
__global__ __launch_bounds__(SCAN_B) void k_scanz(
        const uint32* __restrict__ cnt, int* __restrict__ rp, int* __restrict__ bsum,
        float* __restrict__ dinv, uint4* __restrict__ xh, long long totz,
        int n, int NB) {
    __shared__ int sh[SCAN_B];
    const int b = blockIdx.x;
    const int tid = threadIdx.x;
    if (b < NB) {
        const int i = b * SCAN_B + tid;
        int v = (i < n) ? (int)(cnt[i] >> 16) : 0;
        sh[tid] = v;
        __syncthreads();
        for (int off = 1; off < SCAN_B; off <<= 1) {
            int t = (tid >= off) ? sh[tid - off] : 0;
            __syncthreads();
            sh[tid] += t;
            __syncthreads();
        }
        if (i < n) rp[i] = sh[tid] - v;          // LOCAL exclusive
        if (tid == SCAN_B - 1) bsum[b] = sh[SCAN_B - 1];
    } else {
        const long long idx = (long long)(b - NB) * SCAN_B + tid;
        if (idx < totz) {
            const int i = (int)(idx >> 4);
            const float dv = rsqrtf((float)((cnt[i] & 0xffffu) + 1u));
            uint4 v = xh[idx];
            v.x = bpack(dv * blo(v.x), dv * bhi(v.x));
            v.y = bpack(dv * blo(v.y), dv * bhi(v.y));
            v.z = bpack(dv * blo(v.z), dv * bhi(v.z));
            v.w = bpack(dv * blo(v.w), dv * bhi(v.w));
            xh[idx] = v;
            if ((idx & 15) == 0) dinv[i] = dv;
        }
    }
}

// exclusive scan of bsum in place (single block)
__global__ __launch_bounds__(SCAN_B) void k_scan2(int* __restrict__ bsum, int nb) {
    __shared__ int sh[SCAN_B];
    const int tid = threadIdx.x;
    int v = (tid < nb) ? bsum[tid] : 0;
    sh[tid] = v;
    __syncthreads();
    for (int off = 1; off < SCAN_B; off <<= 1) {
        int t = (tid >= off) ? sh[tid - off] : 0;
        __syncthreads();
        sh[tid] += t;
        __syncthreads();
    }
    if (tid < nb) bsum[tid] = sh[tid] - v;
}

// ATOMIC-FREE CSR fill: slot = rp[r] + bsum[r>>10] + rank16[e]; col only (4 B)
__global__ void k_fill(const int2* __restrict__ rows2, const int2* __restrict__ cols2,
                       const ushort* __restrict__ rank16, const int* __restrict__ rp,
                       const int* __restrict__ bsum, int* __restrict__ e4,
                       int E2, int odd,
                       const int* __restrict__ rows, const int* __restrict__ cols) {
    int t = blockIdx.x * blockDim.x + threadIdx.x;
    if (t < E2) {
        const int2 r2 = rows2[t];
        const int2 c2 = cols2[t];
        const ushort2 rk = *(const ushort2*)(rank16 + 2 * t);
        e4[rp[r2.x] + bsum[r2.x >> 10] + rk.x] = c2.x;
        e4[rp[r2.y] + bsum[r2.y >> 10] + rk.y] = c2.y;
    } else if (t == E2 && odd) {
        const int r = rows[2 * E2];
        e4[rp[r] + bsum[r >> 10] + rank16[2 * E2]] = cols[2 * E2];
    }
}

// z-space hop 1: z1[r] = dinv[r]^2 * (z0[r] + sum_c z0[c]); unweighted gathers.
// ONE ROW PER 64-LANE WAVE, 4 B (bf16x2)/lane, unroll 8, clamp+predicate tail.
__global__ __launch_bounds__(256) void k_spmm(const uint32* __restrict__ xh,
                                              const int* __restrict__ rp,
                                              const int* __restrict__ bsum,
                                              const int* __restrict__ e4,
                                              const float* __restrict__ dinv,
                                              uint32* __restrict__ outh, int n, int Etot) {
    const int row = blockIdx.x * 4 + (threadIdx.x >> 6);
    if (row >= n) return;
    const int l = threadIdx.x & 63;

    const float dv = dinv[row];
    const float sc = dv * dv;

    const uint32 sv = xh[(long long)row * 64 + l];
    float alo = blo(sv);
    float ahi = bhi(sv);

    int e = rp[row] + bsum[row >> 10];
    const int end = (row + 1 < n) ? (rp[row + 1] + bsum[(row + 1) >> 10]) : Etot;
    while (e < end) {
        const int last = end - 1;
        int c[8];
#pragma unroll
        for (int k = 0; k < 8; ++k) {
            const int i = (e + k < last) ? e + k : last;
            c[k] = e4[i];
        }
        uint32 v[8];
#pragma unroll
        for (int k = 0; k < 8; ++k) v[k] = xh[(long long)c[k] * 64 + l];
#pragma unroll
        for (int k = 0; k < 8; ++k) {
            const float w = (e + k <= end - 1) ? 1.0f : 0.0f;
            alo += w * blo(v[k]);
            ahi += w * bhi(v[k]);
        }
        e += 8;
    }

    outh[(long long)row * 64 + l] = bpack(sc * alo, sc * ahi);
}

// FUSED hop2 + GEMM. Block = 128 rows, 8 waves (512 thr).
// Phase 1: wave w computes hop-2 rows w*16..w*16+15 in z-space
//          (x2[r] = dinv[r]*(z1[r]+sum z1[c])), stores bf16x2 into XOR-swizzled
//          LDS (u32 idx = lr*64 + (j ^ ((lr&7)<<2)): write = lane permutation,
//          b128 frag reads 2-way (free, m136)).
// Phase 2: MFMA 128x128 tile from LDS; wave = 32 rows x 64 cols.
// Tail: base clamped to n-128 -> duplicate blocks recompute identical rows.
__global__ __launch_bounds__(512, 6) void k_spgemm(
        const uint32* __restrict__ z1,
        const int* __restrict__ rp, const int* __restrict__ bsum,
        const int* __restrict__ e4, const float* __restrict__ dinv,
        const short8* __restrict__ wfrag, const float* __restrict__ bias,
        float* __restrict__ xout, int n, int Etot) {
    __shared__ uint32 zl[128 * 64];   // 32 KB
    const int w = threadIdx.x >> 6;
    const int l = threadIdx.x & 63;
    long long base = (long long)blockIdx.x * 128;
    if (base + 128 > n) base = (long long)n - 128;

    // ---- phase 1: hop-2 spmm into LDS ----
    for (int lr = w * 16; lr < w * 16 + 16; ++lr) {
        const int row = (int)(base + lr);
        const float dv = dinv[row];
        const uint32 sv = z1[(long long)row * 64 + l];
        float alo = blo(sv);
        float ahi = bhi(sv);

        int e = rp[row] + bsum[row >> 10];
        const int end = (row + 1 < n) ? (rp[row + 1] + bsum[(row + 1) >> 10]) : Etot;
        while (e < end) {
            const int last = end - 1;
            int c[8];
#pragma unroll
            for (int k = 0; k < 8; ++k) {
                const int i = (e + k < last) ? e + k : last;
                c[k] = e4[i];
            }
            uint32 v[8];
#pragma unroll
            for (int k = 0; k < 8; ++k) v[k] = z1[(long long)c[k] * 64 + l];
#pragma unroll
            for (int k = 0; k < 8; ++k) {
                const float ww = (e + k <= end - 1) ? 1.0f : 0.0f;
                alo += ww * blo(v[k]);
                ahi += ww * bhi(v[k]);
            }
            e += 8;
        }
        zl[lr * 64 + (l ^ ((lr & 7) << 2))] = bpack(dv * alo, dv * ahi);
    }
    __syncthreads();

    // ---- phase 2: MFMA from LDS ----
    const int rg = w >> 1;            // 0..3 -> 32 rows each
    const int cg = w & 1;             // 0..1 -> 64 cols each
    const int ls = l & 15;
    const int lg = l >> 4;

    float breg[4];
#pragma unroll
    for (int jt = 0; jt < 4; ++jt) breg[jt] = bias[cg * 64 + jt * 16 + ls];

    f32x4 acc[2][4] = {};

#pragma unroll
    for (int kq = 0; kq < 4; ++kq) {
        short8 af[2];
#pragma unroll
        for (int m = 0; m < 2; ++m) {
            const int lr = rg * 32 + m * 16 + ls;
            const int j = ((kq * 4 + lg) << 2) ^ ((lr & 7) << 2);
            af[m] = *(const short8*)&zl[lr * 64 + j];
        }
#pragma unroll
        for (int jt = 0; jt < 4; ++jt) {
            const short8 bf = wfrag[(kq * 8 + cg * 4 + jt) * 64 + l];
#pragma unroll
            for (int m = 0; m < 2; ++m)
                acc[m][jt] = __builtin_amdgcn_mfma_f32_16x16x32_bf16(
                    af[m], bf, acc[m][jt], 0, 0, 0);
        }
    }

#pragma unroll
    for (int m = 0; m < 2; ++m) {
#pragma unroll
        for (int q = 0; q < 4; ++q) {
            const long long row = base + rg * 32 + m * 16 + lg * 4 + q;
            float* orow = xout + (row << 7) + cg * 64;
#pragma unroll
            for (int jt = 0; jt < 4; ++jt)
                orow[jt * 16 + ls] = acc[m][jt][q] + breg[jt];
        }
    }
}

extern "C" void kernel_launch(void* const* d_in, const int* in_sizes, int n_in,
                              void* d_out, int out_size, void* d_ws, size_t ws_size,
                              hipStream_t stream) {
    const float* x = (const float*)d_in[0];
    const int* ei = (const int*)d_in[1];
    const float* Wm = (const float*)d_in[2];
    const float* bias = (const float*)d_in[3];
    float* out = (float*)d_out;

    const int n = in_sizes[0] / D;
    const int E = in_sizes[1] / 2;
    const int E2 = E >> 1;
    const int odd = E & 1;
    const int NB = (n + SCAN_B - 1) / SCAN_B;

    char* ws = (char*)d_ws;
    size_t off = 0;
    auto alloc = [&](long long bytes) {
        void* p = ws + off;
        off += (size_t)((bytes + 511) & ~511LL);
        return p;
    };
    uint32* cnt   = (uint32*)alloc((long long)n * 4);   // packed degree histogram
    int* rp       = (int*)alloc((long long)n * 4);      // LOCAL exclusive row offsets
    int* bsum     = (int*)alloc((long long)SCAN_B * 4); // scanned block bases
    ushort* rank16= (ushort*)alloc((long long)E * 2);   // per-edge row rank
    int* e4       = (int*)alloc((long long)E * 4);      // CSR col only
    float* dinv   = (float*)alloc((long long)n * 4);
    uint4* xh     = (uint4*)alloc((long long)n * 256);  // bf16 x -> z0
    uint4* z1h    = (uint4*)alloc((long long)n * 256);  // bf16 z1 (hop-1 out)
    uint4* wfrag  = (uint4*)alloc(2048LL * 16);         // 32 KB B-fragments

    const int* rows = ei;
    const int* cols = ei + E;
    const int2* rows2 = (const int2*)rows;
    const int2* cols2 = (const int2*)cols;

    const int B = 256;
    const long long totcvt = (long long)n * 16;         // uint4s
    const int ncount = ceil_div_ll(E2 + 1, B);
    const int ncvt = ceil_div_ll(totcvt, B);
    const int cvtLeft = (ncvt > 5 * ncount) ? (ncvt - 5 * ncount) : 0;
    const int grid_fused = 6 * ncount + cvtLeft + 8;
    const int nzs = ceil_div_ll(totcvt, SCAN_B);

    hipMemsetAsync(cnt, 0, (size_t)n * 4, stream);
    // count (atomic-bound, emits ranks) || cvt || wprep — interleaved
    k_fused<<<grid_fused, B, 0, stream>>>(
        rows2, cols2, cnt, rank16, E2, odd, rows, cols,
        (const float4*)x, xh, totcvt, Wm, wfrag, ncount, ncvt, cvtLeft);

    // local scan || z0 = dinv*x (in place) + dinv write
    k_scanz<<<NB + nzs, SCAN_B, 0, stream>>>(cnt, rp, bsum, dinv, xh, totcvt, n, NB);
    k_scan2<<<1, SCAN_B, 0, stream>>>(bsum, NB);
    k_fill<<<ceil_div_ll(E2 + 1, B), B, 0, stream>>>(
        rows2, cols2, rank16, rp, bsum, e4, E2, odd, rows, cols);

    // hop 1: z1 = dinv^2 * (z0 + sum z0)
    k_spmm<<<ceil_div_ll(n, 4), B, 0, stream>>>(
        (const uint32*)xh, rp, bsum, e4, dinv, (uint32*)z1h, n, E);

    // hop 2 + GEMM fused: out = [dinv*(z1 + sum z1)] @ W^T + b
    k_spgemm<<<ceil_div_ll(n, 128), 512, 0, stream>>>(
        (const uint32*)z1h, rp, bsum, e4, dinv,
        (const short8*)wfrag, bias, out, n, E);
}

// Round 18
// 177.128 us; speedup vs baseline: 1.0177x; 1.0027x over previous
//
#include <hip/hip_runtime.h>

#define D 128
#define SCAN_B 1024

static inline int ceil_div_ll(long long a, int b) { return (int)((a + b - 1) / b); }

typedef unsigned int uint32;
typedef unsigned char uchar;
typedef __attribute__((ext_vector_type(8))) short short8;   // 8 x bf16 (4 VGPRs)
typedef __attribute__((ext_vector_type(4))) float f32x4;    // MFMA C/D

__device__ __forceinline__ float blo(uint32 u) { return __uint_as_float(u << 16); }
__device__ __forceinline__ float bhi(uint32 u) { return __uint_as_float(u & 0xffff0000u); }
__device__ __forceinline__ uint32 bpack(float a, float b) {   // 2x f32 -> bf16x2 RTNE
    uint32 ua = __float_as_uint(a), ub = __float_as_uint(b);
    ua += 0x7fffu + ((ua >> 16) & 1u);
    ub += 0x7fffu + ((ub >> 16) & 1u);
    return (ua >> 16) | (ub & 0xffff0000u);
}

// physical XCD id (0..7), wave-uniform [HW-verified: learn_hip m09]
__device__ __forceinline__ uint32 xcd_id() {
    uint32 x;
    asm volatile("s_getreg_b32 %0, hwreg(HW_REG_XCC_ID)" : "=s"(x));
    return x & 7u;
}

// no-return atomic WITHOUT sc0/sc1 flags: most-local scope the HW allows.
// Safe here because each col8 replica is only ever updated from its own XCD
// (single L2 = single point of atomicity); end-of-kernel release makes the
// values visible to subsequent kernels.
__device__ __forceinline__ void atomic_add_local(uint32* p, uint32 inc) {
    asm volatile("global_atomic_add %0, %1, off" :: "v"(p), "v"(inc) : "memory");
}

// FUSED, roles INTERLEAVED (1 count : 5 cvt per 6 blocks, cvt remainder, 8 wprep).
// Row degree: device-scope atomicAdd, return value = global per-row rank (uchar).
// Col degree: per-XCD replica, half-packed (2 nodes/uint), flag-free asm atomic.
__global__ __launch_bounds__(256) void k_fused(
        const int2* __restrict__ rows2, const int2* __restrict__ cols2,
        uint32* __restrict__ cntrow, uint32* __restrict__ col8, int n2,
        uchar* __restrict__ rank8, int E2, int odd,
        const int* __restrict__ rows, const int* __restrict__ cols,
        const float4* __restrict__ x, uint4* __restrict__ xh, long long totcvt,
        const float* __restrict__ Wm, uint4* __restrict__ wfrag,
        int ncount, int ncvt, int cvtLeft) {
    const int b = blockIdx.x;
    int role, idx;
    if (b < 6 * ncount) {
        const int g = b / 6, p = b - g * 6;
        if (p == 0) { role = 0; idx = g; }
        else        { role = 1; idx = g * 5 + (p - 1); }
    } else if (b < 6 * ncount + cvtLeft) {
        role = 1; idx = 5 * ncount + (b - 6 * ncount);
    } else {
        role = 2; idx = b - 6 * ncount - cvtLeft;
    }

    if (role == 0) {
        uint32* rep = col8 + (long long)xcd_id() * n2;
        const int t = idx * 256 + threadIdx.x;
        if (t < E2) {
            const int2 r2 = rows2[t];
            const int2 c2 = cols2[t];
            const uint32 o0 = atomicAdd(&cntrow[r2.x], 1u);   // device scope (rank)
            atomic_add_local(&rep[c2.x >> 1], (c2.x & 1) ? 0x10000u : 1u);
            const uint32 o1 = atomicAdd(&cntrow[r2.y], 1u);
            atomic_add_local(&rep[c2.y >> 1], (c2.y & 1) ? 0x10000u : 1u);
            uchar2 rk;
            rk.x = (uchar)o0;
            rk.y = (uchar)o1;
            *(uchar2*)(rank8 + 2 * t) = rk;
        } else if (t == E2 && odd) {
            const int r = rows[2 * E2], c = cols[2 * E2];
            const uint32 o = atomicAdd(&cntrow[r], 1u);
            atomic_add_local(&rep[c >> 1], (c & 1) ? 0x10000u : 1u);
            rank8[2 * E2] = (uchar)o;
        }
    } else if (role == 1) {
        if (idx >= ncvt) return;
        const long long i = (long long)idx * 256 + threadIdx.x;
        if (i < totcvt) {
            const float4 a = x[i * 2];
            const float4 c = x[i * 2 + 1];
            uint4 o;
            o.x = bpack(a.x, a.y); o.y = bpack(a.z, a.w);
            o.z = bpack(c.x, c.y); o.w = bpack(c.z, c.w);
            xh[i] = o;
        }
    } else {
        // wprep: lane l of entry (kq*8+jt) holds W[jt*16+(l&15)][kq*32+(l>>4)*8..+7]
        const int t = idx * 256 + threadIdx.x;
        if (t >= 2048) return;
        const int l = t & 63;
        const int pair = t >> 6;
        const int kq = pair >> 3;
        const int jt = pair & 7;
        const int s = l & 15;
        const int g = l >> 4;
        const float* src = Wm + ((long long)(jt * 16 + s) << 7) + kq * 32 + g * 8;
        const float4 w0 = *(const float4*)(src);
        const float4 w1 = *(const float4*)(src + 4);
        uint4 o;
        o.x = bpack(w0.x, w0.y); o.y = bpack(w0.z, w0.w);
        o.z = bpack(w1.x, w1.y); o.w = bpack(w1.z, w1.w);
        wfrag[pair * 64 + l] = o;
    }
}

// FUSED scan+zscale: [0,NB): local exclusive scan of row-degrees -> rp, bsum.
//                    [NB,+): z0 = dinv * xh in place; dinv from col8 replica sum.
__global__ __launch_bounds__(SCAN_B) void k_scanz(
        const uint32* __restrict__ cntrow, const uint32* __restrict__ col8, int n2,
        int* __restrict__ rp, int* __restrict__ bsum,
        float* __restrict__ dinv, uint4* __restrict__ xh, long long totz,
        int n, int NB) {
    __shared__ int sh[SCAN_B];
    const int b = blockIdx.x;
    const int tid = threadIdx.x;
    if (b < NB) {
        const int i = b * SCAN_B + tid;
        int v = (i < n) ? (int)cntrow[i] : 0;
        sh[tid] = v;
        __syncthreads();
        for (int off = 1; off < SCAN_B; off <<= 1) {
            int t = (tid >= off) ? sh[tid - off] : 0;
            __syncthreads();
            sh[tid] += t;
            __syncthreads();
        }
        if (i < n) rp[i] = sh[tid] - v;          // LOCAL exclusive
        if (tid == SCAN_B - 1) bsum[b] = sh[SCAN_B - 1];
    } else {
        const long long idx = (long long)(b - NB) * SCAN_B + tid;
        if (idx < totz) {
            const int i = (int)(idx >> 4);
            uint32 s = 0;
#pragma unroll
            for (int k = 0; k < 8; ++k) {
                const uint32 wv = col8[(long long)k * n2 + (i >> 1)];
                s += (i & 1) ? (wv >> 16) : (wv & 0xffffu);
            }
            const float dv = rsqrtf((float)(s + 1u));
            uint4 v = xh[idx];
            v.x = bpack(dv * blo(v.x), dv * bhi(v.x));
            v.y = bpack(dv * blo(v.y), dv * bhi(v.y));
            v.z = bpack(dv * blo(v.z), dv * bhi(v.z));
            v.w = bpack(dv * blo(v.w), dv * bhi(v.w));
            xh[idx] = v;
            if ((idx & 15) == 0) dinv[i] = dv;
        }
    }
}

// exclusive scan of bsum in place (single block)
__global__ __launch_bounds__(SCAN_B) void k_scan2(int* __restrict__ bsum, int nb) {
    __shared__ int sh[SCAN_B];
    const int tid = threadIdx.x;
    int v = (tid < nb) ? bsum[tid] : 0;
    sh[tid] = v;
    __syncthreads();
    for (int off = 1; off < SCAN_B; off <<= 1) {
        int t = (tid >= off) ? sh[tid - off] : 0;
        __syncthreads();
        sh[tid] += t;
        __syncthreads();
    }
    if (tid < nb) bsum[tid] = sh[tid] - v;
}

// ATOMIC-FREE CSR fill: slot = rp[r] + bsum[r>>10] + rank8[e]; col only (4 B)
__global__ void k_fill(const int2* __restrict__ rows2, const int2* __restrict__ cols2,
                       const uchar* __restrict__ rank8, const int* __restrict__ rp,
                       const int* __restrict__ bsum, int* __restrict__ e4,
                       int E2, int odd,
                       const int* __restrict__ rows, const int* __restrict__ cols) {
    int t = blockIdx.x * blockDim.x + threadIdx.x;
    if (t < E2) {
        const int2 r2 = rows2[t];
        const int2 c2 = cols2[t];
        const uchar2 rk = *(const uchar2*)(rank8 + 2 * t);
        e4[rp[r2.x] + bsum[r2.x >> 10] + rk.x] = c2.x;
        e4[rp[r2.y] + bsum[r2.y >> 10] + rk.y] = c2.y;
    } else if (t == E2 && odd) {
        const int r = rows[2 * E2];
        e4[rp[r] + bsum[r >> 10] + rank8[2 * E2]] = cols[2 * E2];
    }
}

// z-space hop: out[r] = dinv[r]^PW * (z[r] + sum_c z[c]); unweighted gathers.
// ONE ROW PER 64-LANE WAVE, 4 B (bf16x2)/lane, unroll 8, clamp+predicate tail.
template <int PW>
__global__ __launch_bounds__(256) void k_spmm(const uint32* __restrict__ xh,
                                              const int* __restrict__ rp,
                                              const int* __restrict__ bsum,
                                              const int* __restrict__ e4,
                                              const float* __restrict__ dinv,
                                              uint32* __restrict__ outh, int n, int Etot) {
    const int row = blockIdx.x * 4 + (threadIdx.x >> 6);
    if (row >= n) return;
    const int l = threadIdx.x & 63;

    const float dv = dinv[row];
    const float sc = (PW == 2) ? dv * dv : dv;

    const uint32 sv = xh[(long long)row * 64 + l];
    float alo = blo(sv);
    float ahi = bhi(sv);

    int e = rp[row] + bsum[row >> 10];
    const int end = (row + 1 < n) ? (rp[row + 1] + bsum[(row + 1) >> 10]) : Etot;
    while (e < end) {
        const int last = end - 1;
        int c[8];
#pragma unroll
        for (int k = 0; k < 8; ++k) {
            const int i = (e + k < last) ? e + k : last;
            c[k] = e4[i];
        }
        uint32 v[8];
#pragma unroll
        for (int k = 0; k < 8; ++k) v[k] = xh[(long long)c[k] * 64 + l];
#pragma unroll
        for (int k = 0; k < 8; ++k) {
            const float w = (e + k <= end - 1) ? 1.0f : 0.0f;
            alo += w * blo(v[k]);
            ahi += w * bhi(v[k]);
        }
        e += 8;
    }

    outh[(long long)row * 64 + l] = bpack(sc * alo, sc * ahi);
}

// C[r][:] = bf16(A[r][:]) @ bf16(W)^T + b via mfma_f32_16x16x32_bf16.
// Block = 4 waves; wave = 64 rows x 64 cols (acc 64 VGPR) -> 4 blocks/CU.
// Tail waves clamp to [n-64, n): duplicate identical stores, no OOB reads.
__global__ __launch_bounds__(256, 4) void k_gemm(const short8* __restrict__ A8,
                                                 const short8* __restrict__ wfrag,
                                                 const float* __restrict__ bias,
                                                 float* __restrict__ xout, int n) {
    const int wid = threadIdx.x >> 6;
    const int rg = wid >> 1;           // row group (0/1): 64 rows each
    const int cg = wid & 1;            // col group (0/1): 64 cols each
    const int l = threadIdx.x & 63;
    const int ls = l & 15;
    const int lg = l >> 4;
    long long row0 = (long long)blockIdx.x * 128 + rg * 64;
    if (row0 + 64 > n) row0 = (long long)n - 64;

    float breg[4];
#pragma unroll
    for (int jt = 0; jt < 4; ++jt) breg[jt] = bias[cg * 64 + jt * 16 + ls];

    f32x4 acc[4][4] = {};

#pragma unroll
    for (int kq = 0; kq < 4; ++kq) {
        short8 af[4];
#pragma unroll
        for (int m = 0; m < 4; ++m)
            af[m] = A8[(row0 + m * 16 + ls) * 16 + kq * 4 + lg];
#pragma unroll
        for (int jt = 0; jt < 4; ++jt) {
            const short8 bf = wfrag[(kq * 8 + cg * 4 + jt) * 64 + l];
#pragma unroll
            for (int m = 0; m < 4; ++m)
                acc[m][jt] = __builtin_amdgcn_mfma_f32_16x16x32_bf16(
                    af[m], bf, acc[m][jt], 0, 0, 0);
        }
    }

#pragma unroll
    for (int m = 0; m < 4; ++m) {
#pragma unroll
        for (int q = 0; q < 4; ++q) {
            const long long row = row0 + m * 16 + lg * 4 + q;
            float* orow = xout + (row << 7) + cg * 64;
#pragma unroll
            for (int jt = 0; jt < 4; ++jt)
                orow[jt * 16 + ls] = acc[m][jt][q] + breg[jt];
        }
    }
}

extern "C" void kernel_launch(void* const* d_in, const int* in_sizes, int n_in,
                              void* d_out, int out_size, void* d_ws, size_t ws_size,
                              hipStream_t stream) {
    const float* x = (const float*)d_in[0];
    const int* ei = (const int*)d_in[1];
    const float* Wm = (const float*)d_in[2];
    const float* bias = (const float*)d_in[3];
    float* out = (float*)d_out;

    const int n = in_sizes[0] / D;
    const int E = in_sizes[1] / 2;
    const int E2 = E >> 1;
    const int odd = E & 1;
    const int NB = (n + SCAN_B - 1) / SCAN_B;
    const int n2 = (n + 1) >> 1;                        // packed col words per replica

    char* ws = (char*)d_ws;
    size_t off = 0;
    auto alloc = [&](long long bytes) {
        void* p = ws + off;
        off += (size_t)((bytes + 511) & ~511LL);
        return p;
    };
    uint32* cntrow = (uint32*)alloc((long long)n * 4);      // row degree histogram
    uint32* col8   = (uint32*)alloc((long long)n2 * 8 * 4); // 8 XCD col replicas (packed)
    int* rp        = (int*)alloc((long long)n * 4);         // LOCAL exclusive row offsets
    int* bsum      = (int*)alloc((long long)SCAN_B * 4);    // scanned block bases
    uchar* rank8   = (uchar*)alloc((long long)E);           // per-edge global row rank
    int* e4        = (int*)alloc((long long)E * 4);         // CSR col only
    float* dinv    = (float*)alloc((long long)n * 4);
    uint4* xh      = (uint4*)alloc((long long)n * 256);     // bf16 x -> z0 -> hop2 out
    uint4* z1h     = (uint4*)alloc((long long)n * 256);     // bf16 z1
    uint4* wfrag   = (uint4*)alloc(2048LL * 16);            // 32 KB B-fragments

    const int* rows = ei;
    const int* cols = ei + E;
    const int2* rows2 = (const int2*)rows;
    const int2* cols2 = (const int2*)cols;

    const int B = 256;
    const long long totcvt = (long long)n * 16;             // uint4s
    const int ncount = ceil_div_ll(E2 + 1, B);
    const int ncvt = ceil_div_ll(totcvt, B);
    const int cvtLeft = (ncvt > 5 * ncount) ? (ncvt - 5 * ncount) : 0;
    const int grid_fused = 6 * ncount + cvtLeft + 8;
    const int nzs = ceil_div_ll(totcvt, SCAN_B);

    hipMemsetAsync(cntrow, 0, (size_t)n * 4, stream);
    hipMemsetAsync(col8, 0, (size_t)n2 * 32, stream);
    // count (row: device atomics+rank; col: XCD-local flag-free) || cvt || wprep
    k_fused<<<grid_fused, B, 0, stream>>>(
        rows2, cols2, cntrow, col8, n2, rank8, E2, odd, rows, cols,
        (const float4*)x, xh, totcvt, Wm, wfrag, ncount, ncvt, cvtLeft);

    // local scan || z0 = dinv*x (in place, dinv from replica sum) + dinv write
    k_scanz<<<NB + nzs, SCAN_B, 0, stream>>>(
        cntrow, col8, n2, rp, bsum, dinv, xh, totcvt, n, NB);
    k_scan2<<<1, SCAN_B, 0, stream>>>(bsum, NB);
    k_fill<<<ceil_div_ll(E2 + 1, B), B, 0, stream>>>(
        rows2, cols2, rank8, rp, bsum, e4, E2, odd, rows, cols);

    // hop 1 (z1 = dinv^2*(z0 + sum z0)), hop 2 (x2 = dinv*(z1 + sum z1))
    k_spmm<2><<<ceil_div_ll(n, 4), B, 0, stream>>>(
        (const uint32*)xh, rp, bsum, e4, dinv, (uint32*)z1h, n, E);
    k_spmm<1><<<ceil_div_ll(n, 4), B, 0, stream>>>(
        (const uint32*)z1h, rp, bsum, e4, dinv, (uint32*)xh, n, E);

    k_gemm<<<ceil_div_ll(n, 128), B, 0, stream>>>(
        (const short8*)xh, (const short8*)wfrag, bias, out, n);
}

// Round 19
// 174.699 us; speedup vs baseline: 1.0319x; 1.0139x over previous
//
#include <hip/hip_runtime.h>

#define D 128
#define SCAN_B 1024

static inline int ceil_div_ll(long long a, int b) { return (int)((a + b - 1) / b); }

typedef unsigned int uint32;
typedef __attribute__((ext_vector_type(8))) short short8;   // 8 x bf16 (4 VGPRs)
typedef __attribute__((ext_vector_type(4))) float f32x4;    // MFMA C/D

__device__ __forceinline__ float blo(uint32 u) { return __uint_as_float(u << 16); }
__device__ __forceinline__ float bhi(uint32 u) { return __uint_as_float(u & 0xffff0000u); }
__device__ __forceinline__ uint32 bpack(float a, float b) {   // 2x f32 -> bf16x2 RTNE
    uint32 ua = __float_as_uint(a), ub = __float_as_uint(b);
    ua += 0x7fffu + ((ua >> 16) & 1u);
    ub += 0x7fffu + ((ub >> 16) & 1u);
    return (ua >> 16) | (ub & 0xffff0000u);
}

// zero packed histogram
__global__ void k_init(uint32* __restrict__ cnt, int n) {
    int i = blockIdx.x * blockDim.x + threadIdx.x;
    if (i < n) cnt[i] = 0;
}

// FUSED, roles INTERLEAVED (1 count : 5 cvt per 6 blocks, cvt remainder, 8 wprep).
// Count emits per-edge row-rank so CSR fill needs no atomics. The interleave
// is load-bearing: count-only runs SLOWER (r14: 65-69 vs 58.8 us).
__global__ __launch_bounds__(256) void k_fused(
        const int2* __restrict__ rows2, const int2* __restrict__ cols2,
        uint32* __restrict__ cnt, ushort* __restrict__ rank16, int E2, int odd,
        const int* __restrict__ rows, const int* __restrict__ cols,
        const float4* __restrict__ x, uint4* __restrict__ xh, long long totcvt,
        const float* __restrict__ Wm, uint4* __restrict__ wfrag,
        int ncount, int ncvt, int cvtLeft) {
    const int b = blockIdx.x;
    int role, idx;
    if (b < 6 * ncount) {
        const int g = b / 6, p = b - g * 6;
        if (p == 0) { role = 0; idx = g; }
        else        { role = 1; idx = g * 5 + (p - 1); }
    } else if (b < 6 * ncount + cvtLeft) {
        role = 1; idx = 5 * ncount + (b - 6 * ncount);
    } else {
        role = 2; idx = b - 6 * ncount - cvtLeft;
    }

    if (role == 0) {
        const int t = idx * 256 + threadIdx.x;
        if (t < E2) {
            const int2 r2 = rows2[t];
            const int2 c2 = cols2[t];
            const uint32 o0 = atomicAdd(&cnt[r2.x], 0x10000u);
            atomicAdd(&cnt[c2.x], 1u);
            const uint32 o1 = atomicAdd(&cnt[r2.y], 0x10000u);
            atomicAdd(&cnt[c2.y], 1u);
            ushort2 rk;
            rk.x = (ushort)(o0 >> 16);
            rk.y = (ushort)(o1 >> 16);
            *(ushort2*)(rank16 + 2 * t) = rk;
        } else if (t == E2 && odd) {
            const uint32 o = atomicAdd(&cnt[rows[2 * E2]], 0x10000u);
            atomicAdd(&cnt[cols[2 * E2]], 1u);
            rank16[2 * E2] = (ushort)(o >> 16);
        }
    } else if (role == 1) {
        if (idx >= ncvt) return;
        const long long i = (long long)idx * 256 + threadIdx.x;
        if (i < totcvt) {
            const float4 a = x[i * 2];
            const float4 c = x[i * 2 + 1];
            uint4 o;
            o.x = bpack(a.x, a.y); o.y = bpack(a.z, a.w);
            o.z = bpack(c.x, c.y); o.w = bpack(c.z, c.w);
            xh[i] = o;
        }
    } else {
        // wprep: lane l of entry (kq*8+jt) holds W[jt*16+(l&15)][kq*32+(l>>4)*8..+7]
        const int t = idx * 256 + threadIdx.x;
        if (t >= 2048) return;
        const int l = t & 63;
        const int pair = t >> 6;
        const int kq = pair >> 3;
        const int jt = pair & 7;
        const int s = l & 15;
        const int g = l >> 4;
        const float* src = Wm + ((long long)(jt * 16 + s) << 7) + kq * 32 + g * 8;
        const float4 w0 = *(const float4*)(src);
        const float4 w1 = *(const float4*)(src + 4);
        uint4 o;
        o.x = bpack(w0.x, w0.y); o.y = bpack(w0.z, w0.w);
        o.z = bpack(w1.x, w1.y); o.w = bpack(w1.z, w1.w);
        wfrag[pair * 64 + l] = o;
    }
}

// FUSED scan+zscale: [0,NB): local exclusive scan of row-degrees -> rp, bsum.
//                    [NB,+): z0 = dinv * xh in place; writes dinv[] (f32).
__global__ __launch_bounds__(SCAN_B) void k_scanz(
        const uint32* __restrict__ cnt, int* __restrict__ rp, int* __restrict__ bsum,
        float* __restrict__ dinv, uint4* __restrict__ xh, long long totz,
        int n, int NB) {
    __shared__ int sh[SCAN_B];
    const int b = blockIdx.x;
    const int tid = threadIdx.x;
    if (b < NB) {
        const int i = b * SCAN_B + tid;
        int v = (i < n) ? (int)(cnt[i] >> 16) : 0;
        sh[tid] = v;
        __syncthreads();
        for (int off = 1; off < SCAN_B; off <<= 1) {
            int t = (tid >= off) ? sh[tid - off] : 0;
            __syncthreads();
            sh[tid] += t;
            __syncthreads();
        }
        if (i < n) rp[i] = sh[tid] - v;          // LOCAL exclusive (base added by consumers)
        if (tid == SCAN_B - 1) bsum[b] = sh[SCAN_B - 1];
    } else {
        const long long idx = (long long)(b - NB) * SCAN_B + tid;
        if (idx < totz) {
            const int i = (int)(idx >> 4);
            const float dv = rsqrtf((float)((cnt[i] & 0xffffu) + 1u));
            uint4 v = xh[idx];
            v.x = bpack(dv * blo(v.x), dv * bhi(v.x));
            v.y = bpack(dv * blo(v.y), dv * bhi(v.y));
            v.z = bpack(dv * blo(v.z), dv * bhi(v.z));
            v.w = bpack(dv * blo(v.w), dv * bhi(v.w));
            xh[idx] = v;
            if ((idx & 15) == 0) dinv[i] = dv;
        }
    }
}

// exclusive scan of bsum in place (single block)
__global__ __launch_bounds__(SCAN_B) void k_scan2(int* __restrict__ bsum, int nb) {
    __shared__ int sh[SCAN_B];
    const int tid = threadIdx.x;
    int v = (tid < nb) ? bsum[tid] : 0;
    sh[tid] = v;
    __syncthreads();
    for (int off = 1; off < SCAN_B; off <<= 1) {
        int t = (tid >= off) ? sh[tid - off] : 0;
        __syncthreads();
        sh[tid] += t;
        __syncthreads();
    }
    if (tid < nb) bsum[tid] = sh[tid] - v;
}

// ATOMIC-FREE CSR fill: slot = rp[r] + bsum[r>>10] + rank16[e]; col only (4 B)
__global__ void k_fill(const int2* __restrict__ rows2, const int2* __restrict__ cols2,
                       const ushort* __restrict__ rank16, const int* __restrict__ rp,
                       const int* __restrict__ bsum, int* __restrict__ e4,
                       int E2, int odd,
                       const int* __restrict__ rows, const int* __restrict__ cols) {
    int t = blockIdx.x * blockDim.x + threadIdx.x;
    if (t < E2) {
        const int2 r2 = rows2[t];
        const int2 c2 = cols2[t];
        const ushort2 rk = *(const ushort2*)(rank16 + 2 * t);
        e4[rp[r2.x] + bsum[r2.x >> 10] + rk.x] = c2.x;
        e4[rp[r2.y] + bsum[r2.y >> 10] + rk.y] = c2.y;
    } else if (t == E2 && odd) {
        const int r = rows[2 * E2];
        e4[rp[r] + bsum[r >> 10] + rank16[2 * E2]] = cols[2 * E2];
    }
}

// z-space hop: u[r] = z[r] + sum_{c in N(r)} z[c];  out[r] = dinv[r]^PW * u[r]
// ONE ROW PER 64-LANE WAVE, 4 B (bf16x2)/lane. Unweighted gathers, unroll 8.
// CSR bounds assembled inline from local rp + bsum (+E for the last row).
template <int PW>
__global__ __launch_bounds__(256) void k_spmm(const uint32* __restrict__ xh,
                                              const int* __restrict__ rp,
                                              const int* __restrict__ bsum,
                                              const int* __restrict__ e4,
                                              const float* __restrict__ dinv,
                                              uint32* __restrict__ outh, int n, int Etot) {
    const int row = blockIdx.x * 4 + (threadIdx.x >> 6);
    if (row >= n) return;
    const int l = threadIdx.x & 63;

    const float dv = dinv[row];
    const float sc = (PW == 2) ? dv * dv : dv;

    const uint32 sv = xh[(long long)row * 64 + l];
    float alo = blo(sv);
    float ahi = bhi(sv);

    int e = rp[row] + bsum[row >> 10];
    const int end = (row + 1 < n) ? (rp[row + 1] + bsum[(row + 1) >> 10]) : Etot;
    while (e < end) {
        const int last = end - 1;
        int c[8];
#pragma unroll
        for (int k = 0; k < 8; ++k) {
            const int i = (e + k < last) ? e + k : last;
            c[k] = e4[i];
        }
        uint32 v[8];
#pragma unroll
        for (int k = 0; k < 8; ++k) v[k] = xh[(long long)c[k] * 64 + l];
#pragma unroll
        for (int k = 0; k < 8; ++k) {
            const float w = (e + k <= end - 1) ? 1.0f : 0.0f;
            alo += w * blo(v[k]);
            ahi += w * bhi(v[k]);
        }
        e += 8;
    }

    outh[(long long)row * 64 + l] = bpack(sc * alo, sc * ahi);
}

// C[r][:] = bf16(A[r][:]) @ bf16(W)^T + b via mfma_f32_16x16x32_bf16.
// Block = 4 waves; wave = 64 rows x 64 cols (acc 64 VGPR) -> 4 blocks/CU.
// Tail waves clamp to [n-64, n): duplicate identical stores, no OOB reads.
__global__ __launch_bounds__(256, 4) void k_gemm(const short8* __restrict__ A8,
                                                 const short8* __restrict__ wfrag,
                                                 const float* __restrict__ bias,
                                                 float* __restrict__ xout, int n) {
    const int wid = threadIdx.x >> 6;
    const int rg = wid >> 1;           // row group (0/1): 64 rows each
    const int cg = wid & 1;            // col group (0/1): 64 cols each
    const int l = threadIdx.x & 63;
    const int ls = l & 15;
    const int lg = l >> 4;
    long long row0 = (long long)blockIdx.x * 128 + rg * 64;
    if (row0 + 64 > n) row0 = (long long)n - 64;

    float breg[4];
#pragma unroll
    for (int jt = 0; jt < 4; ++jt) breg[jt] = bias[cg * 64 + jt * 16 + ls];

    f32x4 acc[4][4] = {};

#pragma unroll
    for (int kq = 0; kq < 4; ++kq) {
        short8 af[4];
#pragma unroll
        for (int m = 0; m < 4; ++m)
            af[m] = A8[(row0 + m * 16 + ls) * 16 + kq * 4 + lg];
#pragma unroll
        for (int jt = 0; jt < 4; ++jt) {
            const short8 bf = wfrag[(kq * 8 + cg * 4 + jt) * 64 + l];
#pragma unroll
            for (int m = 0; m < 4; ++m)
                acc[m][jt] = __builtin_amdgcn_mfma_f32_16x16x32_bf16(
                    af[m], bf, acc[m][jt], 0, 0, 0);
        }
    }

#pragma unroll
    for (int m = 0; m < 4; ++m) {
#pragma unroll
        for (int q = 0; q < 4; ++q) {
            const long long row = row0 + m * 16 + lg * 4 + q;
            float* orow = xout + (row << 7) + cg * 64;
#pragma unroll
            for (int jt = 0; jt < 4; ++jt)
                orow[jt * 16 + ls] = acc[m][jt][q] + breg[jt];
        }
    }
}

extern "C" void kernel_launch(void* const* d_in, const int* in_sizes, int n_in,
                              void* d_out, int out_size, void* d_ws, size_t ws_size,
                              hipStream_t stream) {
    const float* x = (const float*)d_in[0];
    const int* ei = (const int*)d_in[1];
    const float* Wm = (const float*)d_in[2];
    const float* bias = (const float*)d_in[3];
    float* out = (float*)d_out;

    const int n = in_sizes[0] / D;
    const int E = in_sizes[1] / 2;
    const int E2 = E >> 1;
    const int odd = E & 1;
    const int NB = (n + SCAN_B - 1) / SCAN_B;

    char* ws = (char*)d_ws;
    size_t off = 0;
    auto alloc = [&](long long bytes) {
        void* p = ws + off;
        off += (size_t)((bytes + 511) & ~511LL);
        return p;
    };
    uint32* cnt   = (uint32*)alloc((long long)n * 4);   // packed degree histogram
    int* rp       = (int*)alloc((long long)n * 4);      // LOCAL exclusive row offsets
    int* bsum     = (int*)alloc((long long)SCAN_B * 4); // scanned block bases
    ushort* rank16= (ushort*)alloc((long long)E * 2);   // per-edge row rank
    int* e4       = (int*)alloc((long long)E * 4);      // CSR col only
    float* dinv   = (float*)alloc((long long)n * 4);
    uint4* xh     = (uint4*)alloc((long long)n * 256);  // bf16 x -> z0 -> hop2 out
    uint4* x1h    = (uint4*)alloc((long long)n * 256);  // bf16 z1
    uint4* wfrag  = (uint4*)alloc(2048LL * 16);         // 32 KB B-fragments

    const int* rows = ei;
    const int* cols = ei + E;
    const int2* rows2 = (const int2*)rows;
    const int2* cols2 = (const int2*)cols;

    const int B = 256;
    const long long totcvt = (long long)n * 16;         // uint4s
    const int ncount = ceil_div_ll(E2 + 1, B);
    const int ncvt = ceil_div_ll(totcvt, B);
    const int cvtLeft = (ncvt > 5 * ncount) ? (ncvt - 5 * ncount) : 0;
    const int grid_fused = 6 * ncount + cvtLeft + 8;
    const int nzs = ceil_div_ll(totcvt, SCAN_B);

    k_init<<<ceil_div_ll(n, B), B, 0, stream>>>(cnt, n);
    // count (atomic-bound, emits ranks) || cvt || wprep — interleaved
    k_fused<<<grid_fused, B, 0, stream>>>(
        rows2, cols2, cnt, rank16, E2, odd, rows, cols,
        (const float4*)x, xh, totcvt, Wm, wfrag, ncount, ncvt, cvtLeft);

    // local scan || z0 = dinv*x (in place) + dinv write
    k_scanz<<<NB + nzs, SCAN_B, 0, stream>>>(cnt, rp, bsum, dinv, xh, totcvt, n, NB);
    k_scan2<<<1, SCAN_B, 0, stream>>>(bsum, NB);
    // atomic-free CSR fill (col-only, base assembled inline)
    k_fill<<<ceil_div_ll(E2 + 1, B), B, 0, stream>>>(
        rows2, cols2, rank16, rp, bsum, e4, E2, odd, rows, cols);

    // hop 1 (z1 = dinv^2*(z0 + sum z0)), hop 2 (x2 = dinv*(z1 + sum z1))
    k_spmm<2><<<ceil_div_ll(n, 4), B, 0, stream>>>(
        (const uint32*)xh, rp, bsum, e4, dinv, (uint32*)x1h, n, E);
    k_spmm<1><<<ceil_div_ll(n, 4), B, 0, stream>>>(
        (const uint32*)x1h, rp, bsum, e4, dinv, (uint32*)xh, n, E);

    k_gemm<<<ceil_div_ll(n, 128), B, 0, stream>>>(
        (const short8*)xh, (const short8*)wfrag, bias, out, n);
}